// Round 4
// baseline (395.891 us; speedup 1.0000x reference)
//
#include <hip/hip_runtime.h>
#include <hip/hip_bf16.h>
#include <math.h>

#define B_BATCH 8
#define SEQ 2048
#define DIM 768
#define E3 2304   // 3*DIM

typedef __bf16 bf16x8 __attribute__((ext_vector_type(8)));
typedef float floatx4 __attribute__((ext_vector_type(4)));

__device__ __forceinline__ void load_lds_16B(const __hip_bfloat16* g, __hip_bfloat16* l) {
    __builtin_amdgcn_global_load_lds((const __attribute__((address_space(1))) void*)g,
                                     (__attribute__((address_space(3))) void*)l, 16, 0, 0);
}

#define MEMFENCE asm volatile("" ::: "memory")
#define BAR() do { MEMFENCE; __builtin_amdgcn_s_barrier(); MEMFENCE; } while (0)
#define WAITVM(N) asm volatile("s_waitcnt vmcnt(" #N ")" ::: "memory")

template<typename T> __device__ __forceinline__ T to_out(float v);
template<> __device__ __forceinline__ float to_out<float>(float v) { return v; }
template<> __device__ __forceinline__ __hip_bfloat16 to_out<__hip_bfloat16>(float v) { return __float2bfloat16(v); }

// fp32 -> bf16 conversion, 8 elements per thread
__global__ __launch_bounds__(256, 4)
void cvt_f32_bf16(const float* __restrict__ in, __hip_bfloat16* __restrict__ out, long n8)
{
    const long i = (long)blockIdx.x * blockDim.x + threadIdx.x;
    if (i >= n8) return;
    const float4* p = (const float4*)in + i * 2;
    const float4 a = p[0], b = p[1];
    union { uint4 u; __hip_bfloat16 h[8]; } t;
    t.h[0] = __float2bfloat16(a.x); t.h[1] = __float2bfloat16(a.y);
    t.h[2] = __float2bfloat16(a.z); t.h[3] = __float2bfloat16(a.w);
    t.h[4] = __float2bfloat16(b.x); t.h[5] = __float2bfloat16(b.y);
    t.h[6] = __float2bfloat16(b.z); t.h[7] = __float2bfloat16(b.w);
    ((uint4*)out)[i] = t.u;
}

// 64x64 LDS-tiled transpose: out[c][r] = in[r][c].  grid (rows/64, cols/64, Z)
__global__ __launch_bounds__(256, 4)
void transpose64(const __hip_bfloat16* __restrict__ in, long ldi, long si,
                 __hip_bfloat16* __restrict__ out, long ldo, long so)
{
    __shared__ __hip_bfloat16 t[64][65];   // +1 pad
    in  += (long)blockIdx.z * si;
    out += (long)blockIdx.z * so;
    const int r0 = blockIdx.x * 64;
    const int c0 = blockIdx.y * 64;
    const int tid = threadIdx.x;
    const int r  = tid >> 3;
    const int c8 = (tid & 7) * 8;
#pragma unroll
    for (int h = 0; h < 2; ++h) {
        const int row = r + h * 32;
        union { uint4 u; __hip_bfloat16 v[8]; } tmp;
        tmp.u = *(const uint4*)(in + (long)(r0 + row) * ldi + c0 + c8);
#pragma unroll
        for (int j = 0; j < 8; ++j) t[row][c8 + j] = tmp.v[j];
    }
    __syncthreads();
#pragma unroll
    for (int h = 0; h < 2; ++h) {
        const int cr = r + h * 32;
        union { uint4 u; __hip_bfloat16 v[8]; } tmp;
#pragma unroll
        for (int j = 0; j < 8; ++j) tmp.v[j] = t[c8 + j][cr];
        *(uint4*)(out + (long)(c0 + cr) * ldo + r0 + c8) = tmp.u;
    }
}

// ------------- 256x256 16-wave GEMM, BK=32, 4-buffer ring pipeline -------------
// C[M x N] = f( A [M x K] * B^T ), B is [N x K] row-major.  K % 128 == 0.
// EPI = 0: C = scale*AB^T + bias
// EPI = 1: C = exp(scale*AB^T); fp32 row sums atomically added to rs[]
// EPI = 2: C = (AB^T) * (1/rs[row])
//
// Rationale (r3 counters: MfmaUtil 18%, VALUBusy 12%, Occ 18% — latency-bound at
// 2 waves/SIMD): 1024 threads = 16 waves = 4 waves/SIMD.  One phase per K-tile
// of 32: 8 ds_read_b128 + 2 global_load_lds + 16 INDEPENDENT MFMA + 2 barriers.
//
// LDS: SA/SB = [4 bufs][256 rows][32 cols] bf16 = 128 KiB total.  Tile t lives
// in buf t&3.  Phase t stages tile t+3 (3 phases ≈ 900cy slack ≥ HBM latency).
// vmcnt ledger (2 loads/phase/wave): after phase-t stage, outstanding =
// {t+1,t+2,t+3}x2 = 6 -> WAITVM(4) drains exactly tile t+1.  Tail: t==NT-3 ->
// WAITVM(2), t==NT-2 -> WAITVM(0).  Overwrite safety: buf[(t+3)&3]'s previous
// occupant (tile t-1) was consumed by MFMA before phase t-1's closing barrier.
//
// Swizzle (both-sides, rule #21): row = 64B = 4 chunks of 16B.  Physical chunk
// = (k_group + (row>>1)) & 3.  Read side applies the rotation; the global
// source column is counter-rotated so global_load_lds's linear lane*16B dest
// lands each chunk at its physical slot.  Bank coverage per wave-read: slots
// (fr&1)*4 + ((fr>>1)+g)&3 hit exactly 8x each -> conflict-free (b128 minimum).
__device__ __forceinline__ floatx4 mfma_bf16(bf16x8 a, bf16x8 b, floatx4 c)
{
    return __builtin_amdgcn_mfma_f32_16x16x32_bf16(a, b, c, 0, 0, 0);
}

template<typename OutT, int EPI>
__global__ __launch_bounds__(1024, 1)
void gemm16w(const __hip_bfloat16* __restrict__ A, long lda, long sA,
             const __hip_bfloat16* __restrict__ Bm, long ldb, long sB,
             OutT* __restrict__ C, long ldc, long sC,
             const float* __restrict__ bias,
             float* __restrict__ rs, long srs,
             float scale, int K, int MB, int NB)
{
    __shared__ __hip_bfloat16 SA[4][256 * 32];   // 64 KB
    __shared__ __hip_bfloat16 SB[4][256 * 32];   // 64 KB -> exactly 128 KiB

    // bijective XCD swizzle (every grid here is a multiple of 8)
    const int nwg  = gridDim.x;
    const int orig = blockIdx.x;
    const int wgid = (orig & 7) * (nwg >> 3) + (orig >> 3);
    const int zblk = wgid / (MB * NB);
    const int rem  = wgid - zblk * (MB * NB);
    const int mblk = rem / NB;
    const int nblk = rem - mblk * NB;

    A  += (long)zblk * sA;
    Bm += (long)zblk * sB;
    C  += (long)zblk * sC;
    if constexpr (EPI != 0) rs += (long)zblk * srs;
    const int m0 = mblk * 256, n0 = nblk * 256;

    const int tid  = threadIdx.x;
    const int wid  = tid >> 6, lane = tid & 63;
    const int wrow = wid >> 2, wcol = wid & 3;     // 4 (M) x 4 (N) waves
    const int fr   = lane & 15, g = lane >> 4;     // MFMA frag row / k-group

    // --- staging: wave wid covers tile rows [wid*16, wid*16+16), 4 lanes/row ---
    const int grow = wid * 16 + (lane >> 2);                 // row within tile
    const int gcs  = (((lane & 3) - ((grow >> 1) & 3)) & 3) * 8;  // counter-rotated col
    const long offAst = (long)grow * lda + gcs;
    const long offBst = (long)grow * ldb + gcs;
    const __hip_bfloat16* Ag = A  + (long)m0 * lda;
    const __hip_bfloat16* Bg = Bm + (long)n0 * ldb;

    // --- read offsets (bytes), rotation swizzle applied ---
    int offArd[4], offBrd[4];
#pragma unroll
    for (int i = 0; i < 4; ++i) {
        const int ra = wrow * 64 + i * 16 + fr;
        offArd[i] = ra * 64 + (((g + (ra >> 1)) & 3) << 4);
        const int rb = wcol * 64 + i * 16 + fr;
        offBrd[i] = rb * 64 + (((g + (rb >> 1)) & 3) << 4);
    }

    floatx4 acc[4][4] = {};                        // 64 VGPR/AGPR

    const int NT = K >> 5;                         // K-tiles of 32 (NT >= 3, %4==0)

#define STG(t, buf) do { \
        load_lds_16B(Ag + (long)(t) * 32 + offAst, &SA[buf][0] + wid * 512); \
        load_lds_16B(Bg + (long)(t) * 32 + offBst, &SB[buf][0] + wid * 512); \
    } while (0)

    // prologue: tiles 0,1,2 in flight; drain tile 0
    STG(0, 0); STG(1, 1); STG(2, 2);
    WAITVM(4);
    BAR();

    for (int tb = 0; tb < NT; tb += 4) {
#pragma unroll
        for (int u = 0; u < 4; ++u) {
            const int t = tb + u;
            const char* sa = (const char*)&SA[u][0];
            const char* sb = (const char*)&SB[u][0];
            bf16x8 af[4], bf[4];
#pragma unroll
            for (int i = 0; i < 4; ++i) {
                af[i] = *(const bf16x8*)(sa + offArd[i]);
                bf[i] = *(const bf16x8*)(sb + offBrd[i]);
            }
            if (t + 3 < NT) STG(t + 3, (u + 3) & 3);
            BAR();
            __builtin_amdgcn_s_setprio(1);
#pragma unroll
            for (int mi = 0; mi < 4; ++mi)
#pragma unroll
                for (int ni = 0; ni < 4; ++ni)
                    acc[mi][ni] = mfma_bf16(af[mi], bf[ni], acc[mi][ni]);
            __builtin_amdgcn_s_setprio(0);
            if (t < NT - 3)       { WAITVM(4); }
            else if (t == NT - 3) { WAITVM(2); }
            else if (t == NT - 2) { WAITVM(0); }
            BAR();
        }
    }
#undef STG

    // C/D layout: col = lane&15, row = (lane>>4)*4 + reg  [verified m89/m91]
    const int r0w = m0 + wrow * 64;
    const int c0w = n0 + wcol * 64;

    float inv[4][4];
    if constexpr (EPI == 2) {
#pragma unroll
        for (int mi = 0; mi < 4; ++mi)
#pragma unroll
            for (int r = 0; r < 4; ++r)
                inv[mi][r] = 1.0f / rs[r0w + mi * 16 + g * 4 + r];
    }

    float rsume[4][4] = {};   // EPI==1 only

#pragma unroll
    for (int ni = 0; ni < 4; ++ni) {
        const int col = c0w + ni * 16 + fr;
        const float bv = (EPI == 0 && bias) ? bias[col] : 0.0f;
#pragma unroll
        for (int mi = 0; mi < 4; ++mi)
#pragma unroll
        for (int r = 0; r < 4; ++r) {
            const int row = r0w + mi * 16 + g * 4 + r;
            float v = acc[mi][ni][r];
            if constexpr (EPI == 0)      v = v * scale + bv;
            else if constexpr (EPI == 1) { v = __expf(v * scale); rsume[mi][r] += v; }
            else                         v = v * inv[mi][r];
            C[(long)row * ldc + col] = to_out<OutT>(v);
        }
    }

    if constexpr (EPI == 1) {
        // reduce across the 16 fr-lanes (cols); each (mi,r,g) is a distinct row
#pragma unroll
        for (int mi = 0; mi < 4; ++mi)
#pragma unroll
        for (int r = 0; r < 4; ++r) {
            float s = rsume[mi][r];
            s += __shfl_xor(s, 1, 64);
            s += __shfl_xor(s, 2, 64);
            s += __shfl_xor(s, 4, 64);
            s += __shfl_xor(s, 8, 64);
            if (fr == 0)
                atomicAdd(&rs[r0w + mi * 16 + g * 4 + r], s);
        }
    }
}

extern "C" void kernel_launch(void* const* d_in, const int* in_sizes, int n_in,
                              void* d_out, int out_size, void* d_ws, size_t ws_size,
                              hipStream_t stream)
{
    const float* x     = (const float*)d_in[0];
    const float* w_qkv = (const float*)d_in[1];
    const float* b_qkv = (const float*)d_in[2];
    const float* w_prj = (const float*)d_in[3];
    const float* b_prj = (const float*)d_in[4];
    float* out = (float*)d_out;

    const float alpha = 1.0f / (sqrtf((float)DIM) * 3.0f);  // qk scale / temperature

    const size_t XE   = (size_t)B_BATCH * SEQ * DIM;
    const size_t WQE  = (size_t)E3 * DIM;
    const size_t WPE  = (size_t)DIM * DIM;
    const size_t QKVE = (size_t)B_BATCH * SEQ * E3;
    const size_t SE   = (size_t)B_BATCH * SEQ * SEQ;
    const size_t OE   = XE;
    const size_t RSE  = (size_t)B_BATCH * SEQ;             // fp32 row sums
    dim3 blk(256), blkg(1024);

    const size_t full_bytes = (XE + WQE + WPE + QKVE + SE + OE) * sizeof(__hip_bfloat16)
                            + RSE * sizeof(float);

    if (ws_size >= full_bytes) {
        __hip_bfloat16* xb  = (__hip_bfloat16*)d_ws;
        __hip_bfloat16* wqb = xb + XE;
        __hip_bfloat16* wpb = wqb + WQE;
        __hip_bfloat16* qkv = wpb + WPE;
        __hip_bfloat16* S   = qkv + QKVE;
        __hip_bfloat16* O   = S + SE;
        float*          RS  = (float*)(O + OE);
        __hip_bfloat16* Vt  = xb;                      // xb dead after QKV GEMM

        cvt_f32_bf16<<<dim3((XE / 8 + 255) / 256), blk, 0, stream>>>(x, xb, XE / 8);
        cvt_f32_bf16<<<dim3((WQE / 8 + 255) / 256), blk, 0, stream>>>(w_qkv, wqb, WQE / 8);
        cvt_f32_bf16<<<dim3((WPE / 8 + 255) / 256), blk, 0, stream>>>(w_prj, wpb, WPE / 8);
        hipMemsetAsync(RS, 0, RSE * sizeof(float), stream);

        // qkv = x @ w_qkv^T + b   [16384 x 2304]  grid 576
        gemm16w<__hip_bfloat16, 0><<<dim3(64 * 9), blkg, 0, stream>>>(
            xb, DIM, 0, wqb, DIM, 0, qkv, E3, 0, b_qkv, nullptr, 0, 1.0f, DIM, 64, 9);
        // Vt[b] = V[b]^T  [768 x 2048] per batch
        transpose64<<<dim3(SEQ / 64, DIM / 64, B_BATCH), blk, 0, stream>>>(
            qkv + 2 * DIM, E3, (long)SEQ * E3, Vt, SEQ, (long)DIM * SEQ);
        // E = exp(alpha * Q @ K^T), rowsums -> RS  [8][2048 x 2048]  grid 512
        gemm16w<__hip_bfloat16, 1><<<dim3(8 * 8 * B_BATCH), blkg, 0, stream>>>(
            qkv, E3, (long)SEQ * E3, qkv + DIM, E3, (long)SEQ * E3,
            S, SEQ, (long)SEQ * SEQ, nullptr, RS, SEQ, alpha, DIM, 8, 8);
        // O = (E @ Vt^T) / RS[row]  [8][2048 x 768]  grid 192
        gemm16w<__hip_bfloat16, 2><<<dim3(8 * 3 * B_BATCH), blkg, 0, stream>>>(
            S, SEQ, (long)SEQ * SEQ, Vt, SEQ, (long)DIM * SEQ,
            O, DIM, (long)SEQ * DIM, nullptr, RS, SEQ, 1.0f, SEQ, 8, 3);
        // out = O @ w_proj^T + b  [16384 x 768] fp32  grid 192
        gemm16w<float, 0><<<dim3(64 * 3), blkg, 0, stream>>>(
            O, DIM, 0, wpb, DIM, 0, out, DIM, 0, b_prj, nullptr, 0, 1.0f, DIM, 64, 3);
    } else {
        // minimal-workspace fallback: per-batch pipeline (~30 MB scratch)
        const size_t xE  = (size_t)SEQ * DIM;
        const size_t qE  = (size_t)SEQ * E3;
        const size_t sE1 = (size_t)SEQ * SEQ;
        __hip_bfloat16* wqb = (__hip_bfloat16*)d_ws;
        __hip_bfloat16* wpb = wqb + WQE;
        __hip_bfloat16* xb  = wpb + WPE;            // reused as Vt per batch
        __hip_bfloat16* qkv = xb + xE;
        __hip_bfloat16* S   = qkv + qE;
        __hip_bfloat16* O   = S + sE1;
        float*          RS  = (float*)(O + xE);
        __hip_bfloat16* Vt  = xb;

        cvt_f32_bf16<<<dim3((WQE / 8 + 255) / 256), blk, 0, stream>>>(w_qkv, wqb, WQE / 8);
        cvt_f32_bf16<<<dim3((WPE / 8 + 255) / 256), blk, 0, stream>>>(w_prj, wpb, WPE / 8);

        for (int b = 0; b < B_BATCH; ++b) {
            const float* xf = x + (size_t)b * xE;
            cvt_f32_bf16<<<dim3((xE / 8 + 255) / 256), blk, 0, stream>>>(xf, xb, xE / 8);
            hipMemsetAsync(RS, 0, SEQ * sizeof(float), stream);
            gemm16w<__hip_bfloat16, 0><<<dim3(8 * 9), blkg, 0, stream>>>(
                xb, DIM, 0, wqb, DIM, 0, qkv, E3, 0, b_qkv, nullptr, 0, 1.0f, DIM, 8, 9);
            transpose64<<<dim3(SEQ / 64, DIM / 64, 1), blk, 0, stream>>>(
                qkv + 2 * DIM, E3, 0, Vt, SEQ, 0);
            gemm16w<__hip_bfloat16, 1><<<dim3(8 * 8), blkg, 0, stream>>>(
                qkv, E3, 0, qkv + DIM, E3, 0, S, SEQ, 0, nullptr, RS, 0, alpha, DIM, 8, 8);
            gemm16w<__hip_bfloat16, 2><<<dim3(8 * 3), blkg, 0, stream>>>(
                S, SEQ, 0, Vt, SEQ, 0, O, DIM, 0, nullptr, RS, 0, 1.0f, SEQ, 8, 3);
            gemm16w<float, 0><<<dim3(8 * 3), blkg, 0, stream>>>(
                O, DIM, 0, wpb, DIM, 0, out + (size_t)b * xE, DIM, 0, b_prj, nullptr, 0, 1.0f, DIM, 8, 3);
        }
    }
}

// Round 5
// 368.330 us; speedup vs baseline: 1.0748x; 1.0748x over previous
//
#include <hip/hip_runtime.h>
#include <hip/hip_bf16.h>
#include <math.h>

#define B_BATCH 8
#define SEQ 2048
#define DIM 768
#define E3 2304   // 3*DIM

typedef __bf16 bf16x8 __attribute__((ext_vector_type(8)));
typedef float floatx4 __attribute__((ext_vector_type(4)));

__device__ __forceinline__ void load_lds_16B(const __hip_bfloat16* g, __hip_bfloat16* l) {
    __builtin_amdgcn_global_load_lds((const __attribute__((address_space(1))) void*)g,
                                     (__attribute__((address_space(3))) void*)l, 16, 0, 0);
}

template<typename T> __device__ __forceinline__ T to_out(float v);
template<> __device__ __forceinline__ float to_out<float>(float v) { return v; }
template<> __device__ __forceinline__ __hip_bfloat16 to_out<__hip_bfloat16>(float v) { return __float2bfloat16(v); }

// fp32 -> bf16 conversion, 8 elements per thread
__global__ __launch_bounds__(256, 4)
void cvt_f32_bf16(const float* __restrict__ in, __hip_bfloat16* __restrict__ out, long n8)
{
    const long i = (long)blockIdx.x * blockDim.x + threadIdx.x;
    if (i >= n8) return;
    const float4* p = (const float4*)in + i * 2;
    const float4 a = p[0], b = p[1];
    union { uint4 u; __hip_bfloat16 h[8]; } t;
    t.h[0] = __float2bfloat16(a.x); t.h[1] = __float2bfloat16(a.y);
    t.h[2] = __float2bfloat16(a.z); t.h[3] = __float2bfloat16(a.w);
    t.h[4] = __float2bfloat16(b.x); t.h[5] = __float2bfloat16(b.y);
    t.h[6] = __float2bfloat16(b.z); t.h[7] = __float2bfloat16(b.w);
    ((uint4*)out)[i] = t.u;
}

// 64x64 LDS-tiled transpose: out[c][r] = in[r][c].  grid (rows/64, cols/64, Z)
__global__ __launch_bounds__(256, 4)
void transpose64(const __hip_bfloat16* __restrict__ in, long ldi, long si,
                 __hip_bfloat16* __restrict__ out, long ldo, long so)
{
    __shared__ __hip_bfloat16 t[64][65];   // +1 pad
    in  += (long)blockIdx.z * si;
    out += (long)blockIdx.z * so;
    const int r0 = blockIdx.x * 64;   // row base in `in`
    const int c0 = blockIdx.y * 64;   // col base in `in`
    const int tid = threadIdx.x;
    const int r  = tid >> 3;          // 0..31
    const int c8 = (tid & 7) * 8;
#pragma unroll
    for (int h = 0; h < 2; ++h) {
        const int row = r + h * 32;
        union { uint4 u; __hip_bfloat16 v[8]; } tmp;
        tmp.u = *(const uint4*)(in + (long)(r0 + row) * ldi + c0 + c8);
#pragma unroll
        for (int j = 0; j < 8; ++j) t[row][c8 + j] = tmp.v[j];
    }
    __syncthreads();
#pragma unroll
    for (int h = 0; h < 2; ++h) {
        const int cr = r + h * 32;    // output row = input col
        union { uint4 u; __hip_bfloat16 v[8]; } tmp;
#pragma unroll
        for (int j = 0; j < 8; ++j) tmp.v[j] = t[c8 + j][cr];
        *(uint4*)(out + (long)(c0 + cr) * ldo + r0 + c8) = tmp.u;
    }
}

// C[M x N] = f( A [M x K] * B^T ), B is [N x K] row-major.  (r0 baseline
// structure — 2-phase, 16 KB LDS, 3-4 blocks/CU — with three surgical fixes:)
//
// 1. LDS rotation swizzle (both-sides, rule #21): physical 16B-chunk within a
//    64 B row = (logical + (row>>1)) & 3.  Staging counter-rotates the GLOBAL
//    source column (LDS dest stays linear for global_load_lds); frag reads
//    rotate the column.  Both collapse to lane-only formulas:
//      staging col = ((lane&3) - ((sr>>1)&3)) & 3   (chunk*8 ≡ 0 mod 4)
//      read chunk  = (g + (fr>>1)) & 3              (wm>>1, i*8 ≡ 0 mod 4)
//    Wave bank coverage: group (fr&1)*4 + (g+(fr>>1))&3 hit exactly 2x ->
//    2-way = free (m136).  r0's layout was ~8-way (7.08M conflicts/dispatch).
// 2. Coalesced epilogue: store order (mi,r) outer, ni inner -> the four 32 B
//    segments of each 128 B line issue consecutively (write-combine; WRITE was
//    1.55x amplified in r0).
// 3. Row-sum split: EPI=1 (scores) computes fp32 row sums of exp in its
//    epilogue (shfl-reduce over fr + atomicAdd); EPI=2 (PV) just multiplies by
//    1/rs[row].  Removes PV's per-K-step VALU rsum and the lsum LDS exchange.
//
// EPI = 0: C = scale*AB^T + bias
// EPI = 1: C = exp(scale*AB^T); fp32 row sums atomically added into rs[]
// EPI = 2: C = (AB^T) * (1/rs[row])
// 1D grid = MB*NB*ZB.  XCD swizzle decode (audited r0): pairs = MB*ZB %8==0.
template<typename OutT, int EPI>
__global__ __launch_bounds__(256, 2)
void gemm128(const __hip_bfloat16* __restrict__ A, long lda, long sA,
             const __hip_bfloat16* __restrict__ Bm, long ldb, long sB,
             OutT* __restrict__ C, long ldc, long sC,
             const float* __restrict__ bias,
             float* __restrict__ rs, long srs,
             float scale, int K, int MB, int NB)
{
    __shared__ __hip_bfloat16 As[128 * 32];
    __shared__ __hip_bfloat16 Bs[128 * 32];

    const int id    = blockIdx.x;
    const int xcd   = id & 7;
    const int jj    = id >> 3;
    const int pairs = gridDim.x / NB;      // MB*ZB
    const int ppx   = pairs >> 3;
    const int pair  = xcd * ppx + jj / NB;
    const int nblk  = jj % NB;
    const int zblk  = pair / MB;
    const int mblk  = pair % MB;

    A  += (long)zblk * sA;
    Bm += (long)zblk * sB;
    C  += (long)zblk * sC;
    if constexpr (EPI != 0) rs += (long)zblk * srs;

    const int n0   = nblk * 128;
    const int m0   = mblk * 128;
    const int tid  = threadIdx.x;
    const int wave = tid >> 6;
    const int lane = tid & 63;
    const int wm   = (wave & 1) * 64;
    const int wn   = (wave >> 1) * 64;

    // staging: global_load_lds writes LDS at (uniform base) + lane*16B.
    const int sr  = lane >> 2;
    const int scs = ((((lane & 3) - ((sr >> 1) & 3)) & 3)) * 8;   // counter-rotated

    // MFMA A/B fragment: m(or n)=lane&15, k=(lane>>4)*8 + j  [verified m89/m91]
    const int fr  = lane & 15;
    const int g   = lane >> 4;
    const int fks = ((g + (fr >> 1)) & 3) * 8;                    // rotated read col

    floatx4 acc[4][4] = {};

    for (int k0 = 0; k0 < K; k0 += 32) {
#pragma unroll
        for (int c = 0; c < 2; ++c) {
            const int chunk = wave * 2 + c;            // wave-uniform
            const int row   = chunk * 16 + sr;
            load_lds_16B(A  + (long)(m0 + row) * lda + (k0 + scs), As + chunk * 512);
            load_lds_16B(Bm + (long)(n0 + row) * ldb + (k0 + scs), Bs + chunk * 512);
        }
        __syncthreads();

        bf16x8 af[4], bfr[4];
#pragma unroll
        for (int i = 0; i < 4; ++i) {
            af[i]  = *(const bf16x8*)(As + (wm + i * 16 + fr) * 32 + fks);
            bfr[i] = *(const bf16x8*)(Bs + (wn + i * 16 + fr) * 32 + fks);
        }
#pragma unroll
        for (int mi = 0; mi < 4; ++mi)
#pragma unroll
            for (int ni = 0; ni < 4; ++ni)
                acc[mi][ni] = __builtin_amdgcn_mfma_f32_16x16x32_bf16(
                    af[mi], bfr[ni], acc[mi][ni], 0, 0, 0);
        __syncthreads();
    }

    // C/D layout: col = lane&15, row = (lane>>4)*4 + reg  [verified m89/m91]
    const int cr = g * 4;

    float bv[4];
    if constexpr (EPI == 0) {
#pragma unroll
        for (int ni = 0; ni < 4; ++ni)
            bv[ni] = bias ? bias[n0 + wn + ni * 16 + fr] : 0.0f;
    }

#pragma unroll
    for (int mi = 0; mi < 4; ++mi) {
#pragma unroll
        for (int r = 0; r < 4; ++r) {
            const int row = m0 + wm + mi * 16 + cr + r;
            float invv;
            if constexpr (EPI == 2) invv = 1.0f / rs[row];
            float s = 0.0f;
#pragma unroll
            for (int ni = 0; ni < 4; ++ni) {   // 4 consecutive 32B segments = 128B line pair
                const int col = n0 + wn + ni * 16 + fr;
                float v = acc[mi][ni][r];
                if constexpr (EPI == 0)      v = v * scale + bv[ni];
                else if constexpr (EPI == 1) { v = __expf(v * scale); s += v; }
                else                         v = v * invv;
                C[(long)row * ldc + col] = to_out<OutT>(v);
            }
            if constexpr (EPI == 1) {
                // reduce over the 16 fr-lanes (cols); lanes share g -> same row
                s += __shfl_xor(s, 1, 64);
                s += __shfl_xor(s, 2, 64);
                s += __shfl_xor(s, 4, 64);
                s += __shfl_xor(s, 8, 64);
                if (fr == 0) atomicAdd(&rs[row], s);
            }
        }
    }
}

extern "C" void kernel_launch(void* const* d_in, const int* in_sizes, int n_in,
                              void* d_out, int out_size, void* d_ws, size_t ws_size,
                              hipStream_t stream)
{
    const float* x     = (const float*)d_in[0];
    const float* w_qkv = (const float*)d_in[1];
    const float* b_qkv = (const float*)d_in[2];
    const float* w_prj = (const float*)d_in[3];
    const float* b_prj = (const float*)d_in[4];
    float* out = (float*)d_out;

    const float alpha = 1.0f / (sqrtf((float)DIM) * 3.0f);  // qk scale / temperature

    const size_t XE   = (size_t)B_BATCH * SEQ * DIM;   // 12.58M (also Vt size)
    const size_t WQE  = (size_t)E3 * DIM;
    const size_t WPE  = (size_t)DIM * DIM;
    const size_t QKVE = (size_t)B_BATCH * SEQ * E3;
    const size_t SE   = (size_t)B_BATCH * SEQ * SEQ;
    const size_t OE   = XE;
    const size_t RSE  = (size_t)B_BATCH * SEQ;         // fp32 row sums
    dim3 blk(256);

    const size_t full_bytes = (XE + WQE + WPE + QKVE + SE + OE) * sizeof(__hip_bfloat16)
                            + RSE * sizeof(float);

    if (ws_size >= full_bytes) {
        __hip_bfloat16* xb  = (__hip_bfloat16*)d_ws;   // x-bf16, then reused as Vt
        __hip_bfloat16* wqb = xb + XE;
        __hip_bfloat16* wpb = wqb + WQE;
        __hip_bfloat16* qkv = wpb + WPE;
        __hip_bfloat16* S   = qkv + QKVE;              // holds E = exp(alpha*QK^T)
        __hip_bfloat16* O   = S + SE;
        float*          RS  = (float*)(O + OE);
        __hip_bfloat16* Vt  = xb;                      // xb dead after QKV GEMM

        cvt_f32_bf16<<<dim3((XE / 8 + 255) / 256), blk, 0, stream>>>(x, xb, XE / 8);
        cvt_f32_bf16<<<dim3((WQE / 8 + 255) / 256), blk, 0, stream>>>(w_qkv, wqb, WQE / 8);
        cvt_f32_bf16<<<dim3((WPE / 8 + 255) / 256), blk, 0, stream>>>(w_prj, wpb, WPE / 8);
        hipMemsetAsync(RS, 0, RSE * sizeof(float), stream);

        // qkv = x @ w_qkv^T + b   [16384 x 2304]   pairs=128
        gemm128<__hip_bfloat16, 0><<<dim3(128 * 18), blk, 0, stream>>>(
            xb, DIM, 0, wqb, DIM, 0, qkv, E3, 0, b_qkv, nullptr, 0, 1.0f, DIM, 128, 18);
        // Vt[b] = V[b]^T  [768 x 2048] per batch
        transpose64<<<dim3(SEQ / 64, DIM / 64, B_BATCH), blk, 0, stream>>>(
            qkv + 2 * DIM, E3, (long)SEQ * E3, Vt, SEQ, (long)DIM * SEQ);
        // E = exp(alpha * Q @ K^T), rowsums -> RS   [8][2048 x 2048]   pairs=128
        gemm128<__hip_bfloat16, 1><<<dim3(16 * 16 * B_BATCH), blk, 0, stream>>>(
            qkv, E3, (long)SEQ * E3, qkv + DIM, E3, (long)SEQ * E3,
            S, SEQ, (long)SEQ * SEQ, nullptr, RS, SEQ, alpha, DIM, 16, 16);
        // O = (E @ Vt^T) / RS[row]   [8][2048 x 768]   pairs=128
        gemm128<__hip_bfloat16, 2><<<dim3(16 * 6 * B_BATCH), blk, 0, stream>>>(
            S, SEQ, (long)SEQ * SEQ, Vt, SEQ, (long)DIM * SEQ,
            O, DIM, (long)SEQ * DIM, nullptr, RS, SEQ, 1.0f, SEQ, 16, 6);
        // out = O @ w_proj^T + b  [16384 x 768] fp32   pairs=128
        gemm128<float, 0><<<dim3(128 * 6), blk, 0, stream>>>(
            O, DIM, 0, wpb, DIM, 0, out, DIM, 0, b_prj, nullptr, 0, 1.0f, DIM, 128, 6);
    } else {
        // minimal-workspace fallback: per-batch pipeline (~30 MB scratch)
        const size_t xE  = (size_t)SEQ * DIM;
        const size_t qE  = (size_t)SEQ * E3;
        const size_t sE1 = (size_t)SEQ * SEQ;
        __hip_bfloat16* wqb = (__hip_bfloat16*)d_ws;
        __hip_bfloat16* wpb = wqb + WQE;
        __hip_bfloat16* xb  = wpb + WPE;            // reused as Vt per batch
        __hip_bfloat16* qkv = xb + xE;
        __hip_bfloat16* S   = qkv + qE;
        __hip_bfloat16* O   = S + sE1;
        float*          RS  = (float*)(O + xE);
        __hip_bfloat16* Vt  = xb;

        cvt_f32_bf16<<<dim3((WQE / 8 + 255) / 256), blk, 0, stream>>>(w_qkv, wqb, WQE / 8);
        cvt_f32_bf16<<<dim3((WPE / 8 + 255) / 256), blk, 0, stream>>>(w_prj, wpb, WPE / 8);

        for (int b = 0; b < B_BATCH; ++b) {
            const float* xf = x + (size_t)b * xE;
            cvt_f32_bf16<<<dim3((xE / 8 + 255) / 256), blk, 0, stream>>>(xf, xb, xE / 8);
            hipMemsetAsync(RS, 0, SEQ * sizeof(float), stream);
            gemm128<__hip_bfloat16, 0><<<dim3(16 * 18), blk, 0, stream>>>(
                xb, DIM, 0, wqb, DIM, 0, qkv, E3, 0, b_qkv, nullptr, 0, 1.0f, DIM, 16, 18);
            transpose64<<<dim3(SEQ / 64, DIM / 64, 1), blk, 0, stream>>>(
                qkv + 2 * DIM, E3, 0, Vt, SEQ, 0);
            gemm128<__hip_bfloat16, 1><<<dim3(16 * 16), blk, 0, stream>>>(
                qkv, E3, 0, qkv + DIM, E3, 0, S, SEQ, 0, nullptr, RS, 0, alpha, DIM, 16, 16);
            gemm128<__hip_bfloat16, 2><<<dim3(16 * 6), blk, 0, stream>>>(
                S, SEQ, 0, Vt, SEQ, 0, O, DIM, 0, nullptr, RS, 0, 1.0f, SEQ, 16, 6);
            gemm128<float, 0><<<dim3(16 * 6), blk, 0, stream>>>(
                O, DIM, 0, wpb, DIM, 0, out + (size_t)b * xE, DIM, 0, b_prj, nullptr, 0, 1.0f, DIM, 16, 6);
        }
    }
}

// Round 6
// 358.283 us; speedup vs baseline: 1.1050x; 1.0280x over previous
//
#include <hip/hip_runtime.h>
#include <hip/hip_bf16.h>
#include <math.h>

#define B_BATCH 8
#define SEQ 2048
#define DIM 768
#define E3 2304   // 3*DIM

typedef __bf16 bf16x8 __attribute__((ext_vector_type(8)));
typedef float floatx4 __attribute__((ext_vector_type(4)));

__device__ __forceinline__ void load_lds_16B(const __hip_bfloat16* g, __hip_bfloat16* l) {
    __builtin_amdgcn_global_load_lds((const __attribute__((address_space(1))) void*)g,
                                     (__attribute__((address_space(3))) void*)l, 16, 0, 0);
}

template<typename T> __device__ __forceinline__ T to_out(float v);
template<> __device__ __forceinline__ float to_out<float>(float v) { return v; }
template<> __device__ __forceinline__ __hip_bfloat16 to_out<__hip_bfloat16>(float v) { return __float2bfloat16(v); }

// fp32 -> bf16 conversion, 8 elements per thread
__global__ __launch_bounds__(256, 4)
void cvt_f32_bf16(const float* __restrict__ in, __hip_bfloat16* __restrict__ out, long n8)
{
    const long i = (long)blockIdx.x * blockDim.x + threadIdx.x;
    if (i >= n8) return;
    const float4* p = (const float4*)in + i * 2;
    const float4 a = p[0], b = p[1];
    union { uint4 u; __hip_bfloat16 h[8]; } t;
    t.h[0] = __float2bfloat16(a.x); t.h[1] = __float2bfloat16(a.y);
    t.h[2] = __float2bfloat16(a.z); t.h[3] = __float2bfloat16(a.w);
    t.h[4] = __float2bfloat16(b.x); t.h[5] = __float2bfloat16(b.y);
    t.h[6] = __float2bfloat16(b.z); t.h[7] = __float2bfloat16(b.w);
    ((uint4*)out)[i] = t.u;
}

// 64x64 LDS-tiled transpose: out[c][r] = in[r][c].  grid (rows/64, cols/64, Z)
__global__ __launch_bounds__(256, 4)
void transpose64(const __hip_bfloat16* __restrict__ in, long ldi, long si,
                 __hip_bfloat16* __restrict__ out, long ldo, long so)
{
    __shared__ __hip_bfloat16 t[64][65];   // +1 pad
    in  += (long)blockIdx.z * si;
    out += (long)blockIdx.z * so;
    const int r0 = blockIdx.x * 64;   // row base in `in`
    const int c0 = blockIdx.y * 64;   // col base in `in`
    const int tid = threadIdx.x;
    const int r  = tid >> 3;          // 0..31
    const int c8 = (tid & 7) * 8;
#pragma unroll
    for (int h = 0; h < 2; ++h) {
        const int row = r + h * 32;
        union { uint4 u; __hip_bfloat16 v[8]; } tmp;
        tmp.u = *(const uint4*)(in + (long)(r0 + row) * ldi + c0 + c8);
#pragma unroll
        for (int j = 0; j < 8; ++j) t[row][c8 + j] = tmp.v[j];
    }
    __syncthreads();
#pragma unroll
    for (int h = 0; h < 2; ++h) {
        const int cr = r + h * 32;    // output row = input col
        union { uint4 u; __hip_bfloat16 v[8]; } tmp;
#pragma unroll
        for (int j = 0; j < 8; ++j) tmp.v[j] = t[c8 + j][cr];
        *(uint4*)(out + (long)(c0 + cr) * ldo + r0 + c8) = tmp.u;
    }
}

// C[M x N] = f( A [M x K] * B^T ), B is [N x K] row-major.  K % 64 == 0.
// r5 structure (2-phase, rotation-swizzled LDS, 0 bank conflicts, coalesced
// epilogue, row-sum split) with ONE change: BK 32 -> 64.
//
// Mechanism (r5 post-mortem): each iteration's __syncthreads() after staging
// drains vmcnt(0), exposing full global-load latency (~200-900 cy) per
// iteration against only ~78 cy/SIMD of MFMA work.  Doubling BK halves the
// number of exposed-latency windows, barriers, and drains per unit K while
// doubling MFMA work per window (~156 cy/SIMD).  LDS 16->32 KB still allows
// 5 blocks/CU of cross-block overlap (no m132 occupancy cliff).
//
// Each 32-k half is a structurally identical [128][32] buffer, so the r5
// swizzle applies per-half unchanged:
//   staging col = ((lane&3) - ((sr>>1)&3)) & 3    (counter-rotated global src)
//   read chunk  = (g + (fr>>1)) & 3               (rotated read col)
// Wave bank coverage even (2x per slot) -> conflict-free [measured r5: 0].
//
// EPI = 0: C = scale*AB^T + bias
// EPI = 1: C = exp(scale*AB^T); fp32 row sums atomically added into rs[]
// EPI = 2: C = (AB^T) * (1/rs[row])
// 1D grid = MB*NB*ZB.  XCD swizzle decode (audited r0): pairs = MB*ZB %8==0.
template<typename OutT, int EPI>
__global__ __launch_bounds__(256, 2)
void gemm128(const __hip_bfloat16* __restrict__ A, long lda, long sA,
             const __hip_bfloat16* __restrict__ Bm, long ldb, long sB,
             OutT* __restrict__ C, long ldc, long sC,
             const float* __restrict__ bias,
             float* __restrict__ rs, long srs,
             float scale, int K, int MB, int NB)
{
    __shared__ __hip_bfloat16 As[2][128 * 32];   // two 32-k halves, 8 KB each
    __shared__ __hip_bfloat16 Bs[2][128 * 32];   // total 32 KB

    const int id    = blockIdx.x;
    const int xcd   = id & 7;
    const int jj    = id >> 3;
    const int pairs = gridDim.x / NB;      // MB*ZB
    const int ppx   = pairs >> 3;
    const int pair  = xcd * ppx + jj / NB;
    const int nblk  = jj % NB;
    const int zblk  = pair / MB;
    const int mblk  = pair % MB;

    A  += (long)zblk * sA;
    Bm += (long)zblk * sB;
    C  += (long)zblk * sC;
    if constexpr (EPI != 0) rs += (long)zblk * srs;

    const int n0   = nblk * 128;
    const int m0   = mblk * 128;
    const int tid  = threadIdx.x;
    const int wave = tid >> 6;
    const int lane = tid & 63;
    const int wm   = (wave & 1) * 64;
    const int wn   = (wave >> 1) * 64;

    // staging: global_load_lds writes LDS at (uniform base) + lane*16B.
    const int sr  = lane >> 2;
    const int scs = ((((lane & 3) - ((sr >> 1) & 3)) & 3)) * 8;   // counter-rotated

    // MFMA A/B fragment: m(or n)=lane&15, k=(lane>>4)*8 + j  [verified m89/m91]
    const int fr  = lane & 15;
    const int g   = lane >> 4;
    const int fks = ((g + (fr >> 1)) & 3) * 8;                    // rotated read col

    floatx4 acc[4][4] = {};

    for (int k0 = 0; k0 < K; k0 += 64) {
#pragma unroll
        for (int h = 0; h < 2; ++h)
#pragma unroll
        for (int c = 0; c < 2; ++c) {
            const int chunk = wave * 2 + c;            // wave-uniform
            const int row   = chunk * 16 + sr;
            load_lds_16B(A  + (long)(m0 + row) * lda + (k0 + h * 32 + scs), As[h] + chunk * 512);
            load_lds_16B(Bm + (long)(n0 + row) * ldb + (k0 + h * 32 + scs), Bs[h] + chunk * 512);
        }
        __syncthreads();

#pragma unroll
        for (int h = 0; h < 2; ++h) {
            bf16x8 af[4], bfr[4];
#pragma unroll
            for (int i = 0; i < 4; ++i) {
                af[i]  = *(const bf16x8*)(As[h] + (wm + i * 16 + fr) * 32 + fks);
                bfr[i] = *(const bf16x8*)(Bs[h] + (wn + i * 16 + fr) * 32 + fks);
            }
#pragma unroll
            for (int mi = 0; mi < 4; ++mi)
#pragma unroll
                for (int ni = 0; ni < 4; ++ni)
                    acc[mi][ni] = __builtin_amdgcn_mfma_f32_16x16x32_bf16(
                        af[mi], bfr[ni], acc[mi][ni], 0, 0, 0);
        }
        __syncthreads();
    }

    // C/D layout: col = lane&15, row = (lane>>4)*4 + reg  [verified m89/m91]
    const int cr = g * 4;

    float bv[4];
    if constexpr (EPI == 0) {
#pragma unroll
        for (int ni = 0; ni < 4; ++ni)
            bv[ni] = bias ? bias[n0 + wn + ni * 16 + fr] : 0.0f;
    }

#pragma unroll
    for (int mi = 0; mi < 4; ++mi) {
#pragma unroll
        for (int r = 0; r < 4; ++r) {
            const int row = m0 + wm + mi * 16 + cr + r;
            float invv;
            if constexpr (EPI == 2) invv = 1.0f / rs[row];
            float s = 0.0f;
#pragma unroll
            for (int ni = 0; ni < 4; ++ni) {   // 4 consecutive 32B segments per row
                const int col = n0 + wn + ni * 16 + fr;
                float v = acc[mi][ni][r];
                if constexpr (EPI == 0)      v = v * scale + bv[ni];
                else if constexpr (EPI == 1) { v = __expf(v * scale); s += v; }
                else                         v = v * invv;
                C[(long)row * ldc + col] = to_out<OutT>(v);
            }
            if constexpr (EPI == 1) {
                // reduce over the 16 fr-lanes (cols); lanes share g -> same row
                s += __shfl_xor(s, 1, 64);
                s += __shfl_xor(s, 2, 64);
                s += __shfl_xor(s, 4, 64);
                s += __shfl_xor(s, 8, 64);
                if (fr == 0) atomicAdd(&rs[row], s);
            }
        }
    }
}

extern "C" void kernel_launch(void* const* d_in, const int* in_sizes, int n_in,
                              void* d_out, int out_size, void* d_ws, size_t ws_size,
                              hipStream_t stream)
{
    const float* x     = (const float*)d_in[0];
    const float* w_qkv = (const float*)d_in[1];
    const float* b_qkv = (const float*)d_in[2];
    const float* w_prj = (const float*)d_in[3];
    const float* b_prj = (const float*)d_in[4];
    float* out = (float*)d_out;

    const float alpha = 1.0f / (sqrtf((float)DIM) * 3.0f);  // qk scale / temperature

    const size_t XE   = (size_t)B_BATCH * SEQ * DIM;   // 12.58M (also Vt size)
    const size_t WQE  = (size_t)E3 * DIM;
    const size_t WPE  = (size_t)DIM * DIM;
    const size_t QKVE = (size_t)B_BATCH * SEQ * E3;
    const size_t SE   = (size_t)B_BATCH * SEQ * SEQ;
    const size_t OE   = XE;
    const size_t RSE  = (size_t)B_BATCH * SEQ;         // fp32 row sums
    dim3 blk(256);

    const size_t full_bytes = (XE + WQE + WPE + QKVE + SE + OE) * sizeof(__hip_bfloat16)
                            + RSE * sizeof(float);

    if (ws_size >= full_bytes) {
        __hip_bfloat16* xb  = (__hip_bfloat16*)d_ws;   // x-bf16, then reused as Vt
        __hip_bfloat16* wqb = xb + XE;
        __hip_bfloat16* wpb = wqb + WQE;
        __hip_bfloat16* qkv = wpb + WPE;
        __hip_bfloat16* S   = qkv + QKVE;              // holds E = exp(alpha*QK^T)
        __hip_bfloat16* O   = S + SE;
        float*          RS  = (float*)(O + OE);
        __hip_bfloat16* Vt  = xb;                      // xb dead after QKV GEMM

        cvt_f32_bf16<<<dim3((XE / 8 + 255) / 256), blk, 0, stream>>>(x, xb, XE / 8);
        cvt_f32_bf16<<<dim3((WQE / 8 + 255) / 256), blk, 0, stream>>>(w_qkv, wqb, WQE / 8);
        cvt_f32_bf16<<<dim3((WPE / 8 + 255) / 256), blk, 0, stream>>>(w_prj, wpb, WPE / 8);
        hipMemsetAsync(RS, 0, RSE * sizeof(float), stream);

        // qkv = x @ w_qkv^T + b   [16384 x 2304]   pairs=128
        gemm128<__hip_bfloat16, 0><<<dim3(128 * 18), blk, 0, stream>>>(
            xb, DIM, 0, wqb, DIM, 0, qkv, E3, 0, b_qkv, nullptr, 0, 1.0f, DIM, 128, 18);
        // Vt[b] = V[b]^T  [768 x 2048] per batch
        transpose64<<<dim3(SEQ / 64, DIM / 64, B_BATCH), blk, 0, stream>>>(
            qkv + 2 * DIM, E3, (long)SEQ * E3, Vt, SEQ, (long)DIM * SEQ);
        // E = exp(alpha * Q @ K^T), rowsums -> RS   [8][2048 x 2048]   pairs=128
        gemm128<__hip_bfloat16, 1><<<dim3(16 * 16 * B_BATCH), blk, 0, stream>>>(
            qkv, E3, (long)SEQ * E3, qkv + DIM, E3, (long)SEQ * E3,
            S, SEQ, (long)SEQ * SEQ, nullptr, RS, SEQ, alpha, DIM, 16, 16);
        // O = (E @ Vt^T) / RS[row]   [8][2048 x 768]   pairs=128
        gemm128<__hip_bfloat16, 2><<<dim3(16 * 6 * B_BATCH), blk, 0, stream>>>(
            S, SEQ, (long)SEQ * SEQ, Vt, SEQ, (long)DIM * SEQ,
            O, DIM, (long)SEQ * DIM, nullptr, RS, SEQ, 1.0f, SEQ, 16, 6);
        // out = O @ w_proj^T + b  [16384 x 768] fp32   pairs=128
        gemm128<float, 0><<<dim3(128 * 6), blk, 0, stream>>>(
            O, DIM, 0, wpb, DIM, 0, out, DIM, 0, b_prj, nullptr, 0, 1.0f, DIM, 128, 6);
    } else {
        // minimal-workspace fallback: per-batch pipeline (~30 MB scratch)
        const size_t xE  = (size_t)SEQ * DIM;
        const size_t qE  = (size_t)SEQ * E3;
        const size_t sE1 = (size_t)SEQ * SEQ;
        __hip_bfloat16* wqb = (__hip_bfloat16*)d_ws;
        __hip_bfloat16* wpb = wqb + WQE;
        __hip_bfloat16* xb  = wpb + WPE;            // reused as Vt per batch
        __hip_bfloat16* qkv = xb + xE;
        __hip_bfloat16* S   = qkv + qE;
        __hip_bfloat16* O   = S + sE1;
        float*          RS  = (float*)(O + xE);
        __hip_bfloat16* Vt  = xb;

        cvt_f32_bf16<<<dim3((WQE / 8 + 255) / 256), blk, 0, stream>>>(w_qkv, wqb, WQE / 8);
        cvt_f32_bf16<<<dim3((WPE / 8 + 255) / 256), blk, 0, stream>>>(w_prj, wpb, WPE / 8);

        for (int b = 0; b < B_BATCH; ++b) {
            const float* xf = x + (size_t)b * xE;
            cvt_f32_bf16<<<dim3((xE / 8 + 255) / 256), blk, 0, stream>>>(xf, xb, xE / 8);
            hipMemsetAsync(RS, 0, SEQ * sizeof(float), stream);
            gemm128<__hip_bfloat16, 0><<<dim3(16 * 18), blk, 0, stream>>>(
                xb, DIM, 0, wqb, DIM, 0, qkv, E3, 0, b_qkv, nullptr, 0, 1.0f, DIM, 16, 18);
            transpose64<<<dim3(SEQ / 64, DIM / 64, 1), blk, 0, stream>>>(
                qkv + 2 * DIM, E3, 0, Vt, SEQ, 0);
            gemm128<__hip_bfloat16, 1><<<dim3(16 * 16), blk, 0, stream>>>(
                qkv, E3, 0, qkv + DIM, E3, 0, S, SEQ, 0, nullptr, RS, 0, alpha, DIM, 16, 16);
            gemm128<__hip_bfloat16, 2><<<dim3(16 * 6), blk, 0, stream>>>(
                S, SEQ, 0, Vt, SEQ, 0, O, DIM, 0, nullptr, RS, 0, 1.0f, SEQ, 16, 6);
            gemm128<float, 0><<<dim3(16 * 6), blk, 0, stream>>>(
                O, DIM, 0, wpb, DIM, 0, out + (size_t)b * xE, DIM, 0, b_prj, nullptr, 0, 1.0f, DIM, 16, 6);
        }
    }
}